// Round 11
// baseline (199.795 us; speedup 1.0000x reference)
//
#include <hip/hip_runtime.h>

#define NB    4096
#define TSTEP 256
#define EPB   4       // batch elements per block (MFMA N=16, cols 4..15 idle)
#define DTC   0.01f

typedef _Float16 h8 __attribute__((ext_vector_type(8)));
typedef _Float16 h4 __attribute__((ext_vector_type(4)));
typedef float    f4 __attribute__((ext_vector_type(4)));

#define KE  0.014426950409f   // dt * log2(e)
#define REV 1.59154943e-3f    // dt / (2*pi)  (v_sin/v_cos take revolutions)

// tanh(a) = (E-1)/(E+1), E=exp(2a); upper clamp only (exp2(-inf)->0 -> -1 cleanly)
__device__ __forceinline__ float fast_tanh(float a) {
    float t = fminf(a * 2.885390082f, 126.0f);
    float E = __builtin_amdgcn_exp2f(t);
    return (E - 1.0f) * __builtin_amdgcn_rcpf(E + 1.0f);
}

// LDS map (bytes): y16 f16[16][72] @0 (2304) | u16 f16[16][72] @2304 | y32 f32[16][68] @4608 (4352)
#define U16B  2304
#define Y32B  4608

__global__ void __launch_bounds__(256)
koopman_kernel(const float* __restrict__ x,
               const float* __restrict__ Wc1, const float* __restrict__ bc1,
               const float* __restrict__ Wc2, const float* __restrict__ bc2,
               const float* __restrict__ Wr1, const float* __restrict__ br1,
               const float* __restrict__ Wr2, const float* __restrict__ br2,
               float* __restrict__ out)
{
    const int tid  = threadIdx.x;
    const int lane = tid & 63;
    const int w    = tid >> 6;          // wave id: owns feature tile [16w, 16w+16)
    const int blk  = blockIdx.x;

    __shared__ __align__(16) unsigned char L[Y32B + 16*272];

    const int e  = lane & 15;           // elem column (only e<EPB meaningful)
    const int es = e & (EPB - 1);       // source element for state init (keeps idle cols finite)
    const int g  = lane >> 4;           // k-group

    // ---- persistent A fragments (f16 weights): 16 VGPRs total ----
    const int fa = 16*w + e;            // this lane's A row (feature)
    h8 a1lo, a1hi, a2lo, a2hi;
    {
        const float* r1 = (fa < 48) ? (Wc1 + fa*64) : (Wr1 + (fa-48)*64);
        #pragma unroll
        for (int i = 0; i < 8; ++i) {
            a1lo[i] = (_Float16)r1[8*g + i];
            a1hi[i] = (_Float16)r1[32 + 8*g + i];
        }
        #pragma unroll
        for (int i = 0; i < 8; ++i) {   // stacked block-diag layer 2 (64x64, zero-padded)
            const int k0 = 8*g + i, k1 = k0 + 32;
            float v0, v1;
            if (fa < 48) {
                v0 = (k0 < 48) ? Wc2[fa*48 + k0] : 0.0f;
                v1 = (k1 < 48) ? Wc2[fa*48 + k1] : 0.0f;
            } else {
                v0 = (k0 >= 48) ? Wr2[(fa-48)*16 + (k0-48)] : 0.0f;
                v1 = (k1 >= 48) ? Wr2[(fa-48)*16 + (k1-48)] : 0.0f;
            }
            a2lo[i] = (_Float16)v0;
            a2hi[i] = (_Float16)v1;
        }
    }
    // biases + y state in C/D layout: feat = 16w + 4g + r, elem = e
    float b1v[4], b2v[4], ys[4];
    #pragma unroll
    for (int r = 0; r < 4; ++r) {
        const int f = 16*w + 4*g + r;
        b1v[r] = (f < 48) ? bc1[f] : br1[f-48];
        b2v[r] = (f < 48) ? bc2[f] : br2[f-48];
        ys[r]  = x[(blk*EPB + es)*64 + f];
    }
    const bool cwave = (w < 3);         // waves 0-2: complex pairs; wave 3: real modes

    // ---- loop-invariant addresses ----
    const int rdoff  = e*144 + 16*g;                   // B-frag b128 read
    const int wroff  = e*144 + (16*w + 4*g)*2;         // f16 b64 write
    const int w32off = Y32B + e*272 + (16*w + 4*g)*4;  // f32 b128 write
    // store phase: wave w stores element w's contiguous 64-float row (256B/wave)
    const int stoff = Y32B + w*272 + lane*4;
    float* gp = out + (size_t)(blk*EPB + w) * (TSTEP*64) + lane;

    // ---- initial y16 fill: 16 rows x 64 feats via 256 threads x 4 feats ----
    {
        const int row = tid >> 4, col4 = (tid & 15) * 4;
        const f4 xv = *reinterpret_cast<const f4*>(x + (blk*EPB + (row & (EPB-1)))*64 + col4);
        h4 p; p[0]=(_Float16)xv[0]; p[1]=(_Float16)xv[1]; p[2]=(_Float16)xv[2]; p[3]=(_Float16)xv[3];
        *reinterpret_cast<h4*>(L + row*144 + col4*2) = p;
    }
    __syncthreads();

    for (int t = 0; t < TSTEP; ++t) {
        // ---- layer 1: u = tanh(W1s @ y + b1) on the matrix pipe ----
        const h8 by0 = *reinterpret_cast<const h8*>(L + rdoff);
        const h8 by1 = *reinterpret_cast<const h8*>(L + rdoff + 64);
        f4 a = {b1v[0], b1v[1], b1v[2], b1v[3]};
        a = __builtin_amdgcn_mfma_f32_16x16x32_f16(a1lo, by0, a, 0, 0, 0);
        a = __builtin_amdgcn_mfma_f32_16x16x32_f16(a1hi, by1, a, 0, 0, 0);
        h4 up;
        up[0]=(_Float16)fast_tanh(a[0]); up[1]=(_Float16)fast_tanh(a[1]);
        up[2]=(_Float16)fast_tanh(a[2]); up[3]=(_Float16)fast_tanh(a[3]);
        *reinterpret_cast<h4*>(L + U16B + wroff) = up;
        __syncthreads();

        // ---- layer 2: co/re = W2s @ u + b2 ----
        const h8 bu0 = *reinterpret_cast<const h8*>(L + U16B + rdoff);
        const h8 bu1 = *reinterpret_cast<const h8*>(L + U16B + rdoff + 64);
        f4 c = {b2v[0], b2v[1], b2v[2], b2v[3]};
        c = __builtin_amdgcn_mfma_f32_16x16x32_f16(a2lo, bu0, c, 0, 0, 0);
        c = __builtin_amdgcn_mfma_f32_16x16x32_f16(a2hi, bu1, c, 0, 0, 0);

        // ---- pointwise: pairs are register-local, role is wave-uniform ----
        if (cwave) {
            const float sc0 = __builtin_amdgcn_exp2f(KE * c[0]);
            const float sc1 = __builtin_amdgcn_exp2f(KE * c[2]);
            const float s0 = __builtin_amdgcn_sinf(REV * c[1]) * sc0;
            const float c0 = __builtin_amdgcn_cosf(REV * c[1]) * sc0;
            const float s1 = __builtin_amdgcn_sinf(REV * c[3]) * sc1;
            const float c1 = __builtin_amdgcn_cosf(REV * c[3]) * sc1;
            const float n0 = c0*ys[0] - s0*ys[1];
            const float n1 = s0*ys[0] + c0*ys[1];
            const float n2 = c1*ys[2] - s1*ys[3];
            const float n3 = s1*ys[2] + c1*ys[3];
            ys[0]=n0; ys[1]=n1; ys[2]=n2; ys[3]=n3;
        } else {
            ys[0] *= __builtin_amdgcn_exp2f(KE * c[0]);
            ys[1] *= __builtin_amdgcn_exp2f(KE * c[1]);
            ys[2] *= __builtin_amdgcn_exp2f(KE * c[2]);
            ys[3] *= __builtin_amdgcn_exp2f(KE * c[3]);
        }

        // ---- publish y: f16 for next step's matmul, f32 for output staging ----
        h4 yp;
        yp[0]=(_Float16)ys[0]; yp[1]=(_Float16)ys[1]; yp[2]=(_Float16)ys[2]; yp[3]=(_Float16)ys[3];
        *reinterpret_cast<h4*>(L + wroff) = yp;
        f4 yv = {ys[0], ys[1], ys[2], ys[3]};
        *reinterpret_cast<f4*>(L + w32off) = yv;
        __syncthreads();

        // ---- coalesced output store: wave w -> element w's 256B row ----
        *gp = *reinterpret_cast<const float*>(L + stoff);
        gp += 64;
    }
}

extern "C" void kernel_launch(void* const* d_in, const int* in_sizes, int n_in,
                              void* d_out, int out_size, void* d_ws, size_t ws_size,
                              hipStream_t stream) {
    const float* x   = (const float*)d_in[0];
    const float* Wc1 = (const float*)d_in[1];
    const float* bc1 = (const float*)d_in[2];
    const float* Wc2 = (const float*)d_in[3];
    const float* bc2 = (const float*)d_in[4];
    const float* Wr1 = (const float*)d_in[5];
    const float* br1 = (const float*)d_in[6];
    const float* Wr2 = (const float*)d_in[7];
    const float* br2 = (const float*)d_in[8];
    float* out = (float*)d_out;

    koopman_kernel<<<dim3(NB / EPB), dim3(256), 0, stream>>>(
        x, Wc1, bc1, Wc2, bc2, Wr1, br1, Wr2, br2, out);
}

// Round 12
// 122.492 us; speedup vs baseline: 1.6311x; 1.6311x over previous
//
#include <hip/hip_runtime.h>

#define NB    4096
#define TSTEP 256
#define EPB   16      // batch elements per block (= MFMA N)
#define DTC   0.01f

typedef _Float16 h8 __attribute__((ext_vector_type(8)));
typedef _Float16 h4 __attribute__((ext_vector_type(4)));
typedef float    f4 __attribute__((ext_vector_type(4)));

#define KE  0.014426950409f   // dt * log2(e)
#define REV 1.59154943e-3f    // dt / (2*pi)  (v_sin/v_cos take revolutions)

// tanh(a) = (E-1)/(E+1), E=exp(2a); upper clamp only (exp2(-inf)->0 -> -1 cleanly)
__device__ __forceinline__ float fast_tanh(float a) {
    float t = fminf(a * 2.885390082f, 126.0f);
    float E = __builtin_amdgcn_exp2f(t);
    return (E - 1.0f) * __builtin_amdgcn_rcpf(E + 1.0f);
}

// raw workgroup barrier: LDS visibility only, NO vmcnt drain (stores stay async)
__device__ __forceinline__ void lds_barrier() {
    asm volatile("s_waitcnt lgkmcnt(0)" ::: "memory");
    __builtin_amdgcn_s_barrier();
    asm volatile("" ::: "memory");
}

// LDS map (bytes): y16 f16[16][72] @0 (2304) | u16 f16[16][72] @2304  -- 4608 total
#define U16B  2304

__global__ void __launch_bounds__(256)
koopman_kernel(const float* __restrict__ x,
               const float* __restrict__ Wc1, const float* __restrict__ bc1,
               const float* __restrict__ Wc2, const float* __restrict__ bc2,
               const float* __restrict__ Wr1, const float* __restrict__ br1,
               const float* __restrict__ Wr2, const float* __restrict__ br2,
               float* __restrict__ out)
{
    const int tid  = threadIdx.x;
    const int lane = tid & 63;
    const int w    = tid >> 6;          // wave id: owns feature tile [16w, 16w+16)
    const int blk  = blockIdx.x;

    __shared__ __align__(16) unsigned char L[U16B * 2];

    const int e = lane & 15;            // elem column (B/D col, A row-within-tile)
    const int g = lane >> 4;            // k-group

    // ---- persistent A fragments (f16 weights): 16 VGPRs total ----
    const int fa = 16*w + e;            // this lane's A row (feature)
    h8 a1lo, a1hi, a2lo, a2hi;
    {
        const float* r1 = (fa < 48) ? (Wc1 + fa*64) : (Wr1 + (fa-48)*64);
        #pragma unroll
        for (int i = 0; i < 8; ++i) {
            a1lo[i] = (_Float16)r1[8*g + i];
            a1hi[i] = (_Float16)r1[32 + 8*g + i];
        }
        #pragma unroll
        for (int i = 0; i < 8; ++i) {   // stacked block-diag layer 2 (64x64, zero-padded)
            const int k0 = 8*g + i, k1 = k0 + 32;
            float v0, v1;
            if (fa < 48) {
                v0 = (k0 < 48) ? Wc2[fa*48 + k0] : 0.0f;
                v1 = (k1 < 48) ? Wc2[fa*48 + k1] : 0.0f;
            } else {
                v0 = (k0 >= 48) ? Wr2[(fa-48)*16 + (k0-48)] : 0.0f;
                v1 = (k1 >= 48) ? Wr2[(fa-48)*16 + (k1-48)] : 0.0f;
            }
            a2lo[i] = (_Float16)v0;
            a2hi[i] = (_Float16)v1;
        }
    }
    // biases + y state in C/D layout: feat = 16w + 4g + r, elem = e
    float b1v[4], b2v[4], ys[4];
    #pragma unroll
    for (int r = 0; r < 4; ++r) {
        const int f = 16*w + 4*g + r;
        b1v[r] = (f < 48) ? bc1[f] : br1[f-48];
        b2v[r] = (f < 48) ? bc2[f] : br2[f-48];
        ys[r]  = x[(blk*EPB + e)*64 + f];
    }
    const bool cwave = (w < 3);         // waves 0-2: complex pairs; wave 3: real modes

    // ---- loop-invariant addresses ----
    const int rdoff = e*144 + 16*g;                 // B-frag b128 read
    const int wroff = e*144 + (16*w + 4*g)*2;       // f16 b64 write
    // direct register store: lane (e,g) owns 16B of elem e's 256B row
    float* gp = out + (size_t)(blk*EPB + e) * (TSTEP*64) + 16*w + 4*g;

    // ---- initial y16 fill: 16 rows x 64 feats via 256 threads x 4 feats ----
    {
        const int row = tid >> 4, col4 = (tid & 15) * 4;
        const f4 xv = *reinterpret_cast<const f4*>(x + (blk*EPB + row)*64 + col4);
        h4 p; p[0]=(_Float16)xv[0]; p[1]=(_Float16)xv[1]; p[2]=(_Float16)xv[2]; p[3]=(_Float16)xv[3];
        *reinterpret_cast<h4*>(L + row*144 + col4*2) = p;
    }
    __syncthreads();

    for (int t = 0; t < TSTEP; ++t) {
        // ---- phase 1: u = tanh(W1s @ y + b1); independent MFMAs, then add ----
        const h8 by0 = *reinterpret_cast<const h8*>(L + rdoff);
        const h8 by1 = *reinterpret_cast<const h8*>(L + rdoff + 64);
        f4 aL = {b1v[0], b1v[1], b1v[2], b1v[3]};
        f4 aH = {0.0f, 0.0f, 0.0f, 0.0f};
        aL = __builtin_amdgcn_mfma_f32_16x16x32_f16(a1lo, by0, aL, 0, 0, 0);
        aH = __builtin_amdgcn_mfma_f32_16x16x32_f16(a1hi, by1, aH, 0, 0, 0);
        const f4 a = aL + aH;
        h4 up;
        up[0]=(_Float16)fast_tanh(a[0]); up[1]=(_Float16)fast_tanh(a[1]);
        up[2]=(_Float16)fast_tanh(a[2]); up[3]=(_Float16)fast_tanh(a[3]);
        *reinterpret_cast<h4*>(L + U16B + wroff) = up;
        lds_barrier();

        // ---- phase 2: co/re = W2s @ u + b2 ----
        const h8 bu0 = *reinterpret_cast<const h8*>(L + U16B + rdoff);
        const h8 bu1 = *reinterpret_cast<const h8*>(L + U16B + rdoff + 64);
        f4 cL = {b2v[0], b2v[1], b2v[2], b2v[3]};
        f4 cH = {0.0f, 0.0f, 0.0f, 0.0f};
        cL = __builtin_amdgcn_mfma_f32_16x16x32_f16(a2lo, bu0, cL, 0, 0, 0);
        cH = __builtin_amdgcn_mfma_f32_16x16x32_f16(a2hi, bu1, cH, 0, 0, 0);
        const f4 c = cL + cH;

        // ---- pointwise: pairs register-local, role wave-uniform ----
        if (cwave) {
            const float sc0 = __builtin_amdgcn_exp2f(KE * c[0]);
            const float sc1 = __builtin_amdgcn_exp2f(KE * c[2]);
            const float s0 = __builtin_amdgcn_sinf(REV * c[1]) * sc0;
            const float c0 = __builtin_amdgcn_cosf(REV * c[1]) * sc0;
            const float s1 = __builtin_amdgcn_sinf(REV * c[3]) * sc1;
            const float c1 = __builtin_amdgcn_cosf(REV * c[3]) * sc1;
            const float n0 = c0*ys[0] - s0*ys[1];
            const float n1 = s0*ys[0] + c0*ys[1];
            const float n2 = c1*ys[2] - s1*ys[3];
            const float n3 = s1*ys[2] + c1*ys[3];
            ys[0]=n0; ys[1]=n1; ys[2]=n2; ys[3]=n3;
        } else {
            ys[0] *= __builtin_amdgcn_exp2f(KE * c[0]);
            ys[1] *= __builtin_amdgcn_exp2f(KE * c[1]);
            ys[2] *= __builtin_amdgcn_exp2f(KE * c[2]);
            ys[3] *= __builtin_amdgcn_exp2f(KE * c[3]);
        }

        // ---- publish y (f16 for next matmul) + async direct f32 store ----
        h4 yp;
        yp[0]=(_Float16)ys[0]; yp[1]=(_Float16)ys[1]; yp[2]=(_Float16)ys[2]; yp[3]=(_Float16)ys[3];
        *reinterpret_cast<h4*>(L + wroff) = yp;
        f4 yv = {ys[0], ys[1], ys[2], ys[3]};
        *reinterpret_cast<f4*>(gp) = yv;    // never drained in-loop (raw barriers)
        gp += 64;
        lds_barrier();
    }
}

extern "C" void kernel_launch(void* const* d_in, const int* in_sizes, int n_in,
                              void* d_out, int out_size, void* d_ws, size_t ws_size,
                              hipStream_t stream) {
    const float* x   = (const float*)d_in[0];
    const float* Wc1 = (const float*)d_in[1];
    const float* bc1 = (const float*)d_in[2];
    const float* Wc2 = (const float*)d_in[3];
    const float* bc2 = (const float*)d_in[4];
    const float* Wr1 = (const float*)d_in[5];
    const float* br1 = (const float*)d_in[6];
    const float* Wr2 = (const float*)d_in[7];
    const float* br2 = (const float*)d_in[8];
    float* out = (float*)d_out;

    koopman_kernel<<<dim3(NB / EPB), dim3(256), 0, stream>>>(
        x, Wc1, bc1, Wc2, bc2, Wr1, br1, Wr2, br2, out);
}